// Round 3
// baseline (391.915 us; speedup 1.0000x reference)
//
#include <hip/hip_runtime.h>

// CapsNet forward, fp32.
// Kernel 0: repack conv2 weights to wT[ci][q][co][4] (q=0..20, j=q*4+e<=80)
// Kernel 1: conv1 9x9 VALID stride1: [B,1,28,28] -> [B,16,20,20]
// Kernel 2: conv2 9x9 VALID stride2, LDS-free, weights-in-registers -> u [B,144,8]
// Kernel 3: per-sample u_hat (LDS) + 3 routing iters + squash -> pred, v

__global__ __launch_bounds__(256) void transpose_w2(
    const float* __restrict__ w2, float* __restrict__ wT) {
  int idx = blockIdx.x * 256 + threadIdx.x;   // over 16*21*32*4 = 43008
  if (idx >= 43008) return;
  int e = idx & 3;
  int co = (idx >> 2) & 31;
  int q = (idx >> 7) % 21;
  int ci = idx / (21 * 128);
  int j = q * 4 + e;
  wT[idx] = (j < 81) ? w2[(co * 16 + ci) * 81 + j] : 0.0f;
}

__global__ __launch_bounds__(320) void conv1_kernel(
    const float* __restrict__ in, const float* __restrict__ w,
    const float* __restrict__ bias, float* __restrict__ x1) {
  __shared__ __align__(16) float sIn[784];    // 28x28
  __shared__ float sW[1296];                  // 16x81
  int b = blockIdx.x, t = threadIdx.x;
  const float* inb = in + b * 784;
  for (int i = t; i < 784; i += 320) sIn[i] = inb[i];
  for (int i = t; i < 1296; i += 320) sW[i] = w[i];
  __syncthreads();
  int co = t / 20, oh = t % 20;   // 16*20 = 320 work items
  float bv = bias[co];
  float acc[20];
#pragma unroll
  for (int j = 0; j < 20; ++j) acc[j] = bv;
#pragma unroll
  for (int kh = 0; kh < 9; ++kh) {
    float r[28];
    const float4* row = (const float4*)&sIn[(oh + kh) * 28];
#pragma unroll
    for (int q = 0; q < 7; ++q) {
      float4 v = row[q];
      r[q * 4 + 0] = v.x; r[q * 4 + 1] = v.y; r[q * 4 + 2] = v.z; r[q * 4 + 3] = v.w;
    }
    const float* wr = &sW[co * 81 + kh * 9];
#pragma unroll
    for (int kw = 0; kw < 9; ++kw) {
      float wv = wr[kw];
#pragma unroll
      for (int j = 0; j < 20; ++j) acc[j] += wv * r[kw + j];
    }
  }
  float* outp = x1 + b * 6400 + co * 400 + oh * 20;
#pragma unroll
  for (int q = 0; q < 5; ++q) {
    *(float4*)&outp[q * 4] =
        make_float4(acc[q * 4], acc[q * 4 + 1], acc[q * 4 + 2], acc[q * 4 + 3]);
  }
}

// conv2: thread = (b, co, oh). Lane map t = oh*32+co:
//  - weight float4 loads: 32 consecutive float4 per wave (coalesced, L1)
//  - row float4 loads: 2 unique 80B rows per wave instr (broadcast)
// Per ci: 66 VMEM instrs vs 972 FMA cycles. 6144 waves total.
__global__ __launch_bounds__(192) void conv2_kernel(
    const float* __restrict__ x1, const float* __restrict__ wT,
    const float* __restrict__ bias, float* __restrict__ u) {
  int b = blockIdx.x, t = threadIdx.x;
  int oh = t >> 5, co = t & 31;
  const float* xb = x1 + (size_t)b * 6400;
  const float4* w4 = (const float4*)wT;
  float acc[6] = {0.f, 0.f, 0.f, 0.f, 0.f, 0.f};

  for (int ci = 0; ci < 16; ++ci) {
    float w[84];
    int wbase = ci * (21 * 32) + co;
#pragma unroll
    for (int q = 0; q < 21; ++q) {
      float4 v = w4[wbase + q * 32];
      w[q * 4 + 0] = v.x; w[q * 4 + 1] = v.y;
      w[q * 4 + 2] = v.z; w[q * 4 + 3] = v.w;
    }
    const float* xc = xb + ci * 400;
#pragma unroll
    for (int kh = 0; kh < 9; ++kh) {
      int ih = oh * 2 + kh;
      float r[20];
      const float4* rp = (const float4*)(xc + ih * 20);
#pragma unroll
      for (int q = 0; q < 5; ++q) {
        float4 v = rp[q];
        r[q * 4 + 0] = v.x; r[q * 4 + 1] = v.y;
        r[q * 4 + 2] = v.z; r[q * 4 + 3] = v.w;
      }
#pragma unroll
      for (int kw = 0; kw < 9; ++kw) {
        float wv = w[kh * 9 + kw];
#pragma unroll
        for (int ow = 0; ow < 6; ++ow) acc[ow] += wv * r[ow * 2 + kw];
      }
    }
  }
  float bv = bias[co];
  float* ub = u + (size_t)b * 1152;
  int ib = (co & 3) * 36 + oh * 6;
  int c8 = co >> 2;
#pragma unroll
  for (int ow = 0; ow < 6; ++ow) ub[(ib + ow) * 8 + c8] = acc[ow] + bv;
}

__global__ __launch_bounds__(512) void routing_kernel(
    const float* __restrict__ u, const float* __restrict__ W,
    float* __restrict__ out, int B) {
  __shared__ __align__(16) float uh[23040];   // u_hat [144][160]  (o*16+d)
  __shared__ __align__(16) float us[1152];    // u [144][8]
  __shared__ float blog[1440];                // b [144][10]
  __shared__ float cc[1440];                  // c [144][10]
  __shared__ __align__(16) float vv[160];     // v [10][16]
  __shared__ float ss[160];                   // s [10][16]
  int b = blockIdx.x, t = threadIdx.x;
  for (int i = t; i < 1152; i += 512) us[i] = u[b * 1152 + i];
  for (int i = t; i < 1440; i += 512) blog[i] = 0.0f;
  __syncthreads();
  const float4* W4 = (const float4*)W;
  for (int idx = t; idx < 23040; idx += 512) {
    int i = idx / 160;
    float4 wa = W4[idx * 2], wb = W4[idx * 2 + 1];
    const float4* up = (const float4*)&us[i * 8];
    float4 ua = up[0], ub2 = up[1];
    uh[idx] = wa.x * ua.x + wa.y * ua.y + wa.z * ua.z + wa.w * ua.w +
              wb.x * ub2.x + wb.y * ub2.y + wb.z * ub2.z + wb.w * ub2.w;
  }
  __syncthreads();

  for (int it = 0; it < 3; ++it) {
    if (it > 0) {
      if (t < 144) {
        const float* br = &blog[t * 10];
        float mx = br[0];
#pragma unroll
        for (int o = 1; o < 10; ++o) mx = fmaxf(mx, br[o]);
        float e[10];
        float sum = 0.f;
#pragma unroll
        for (int o = 0; o < 10; ++o) { e[o] = __expf(br[o] - mx); sum += e[o]; }
        float inv = 1.0f / sum;
#pragma unroll
        for (int o = 0; o < 10; ++o) cc[t * 10 + o] = e[o] * inv;
      }
      __syncthreads();
    }
    if (t < 160) {
      int o = t >> 4;
      float acc = 0.f;
      if (it == 0) {
        for (int i = 0; i < 144; ++i) acc += uh[i * 160 + t];
        acc *= 0.1f;
      } else {
        for (int i = 0; i < 144; ++i) acc += cc[i * 10 + o] * uh[i * 160 + t];
      }
      ss[t] = acc;
    }
    __syncthreads();
    if (t < 10) {
      float sq = 0.f;
#pragma unroll
      for (int d = 0; d < 16; ++d) { float x = ss[t * 16 + d]; sq += x * x; }
      float coef = (sq / (1.0f + sq)) / sqrtf(sq + 1e-8f);
#pragma unroll
      for (int d = 0; d < 16; ++d) vv[t * 16 + d] = coef * ss[t * 16 + d];
      if (it == 2) out[b * 10 + t] = coef * sqrtf(sq);
    }
    __syncthreads();
    if (it < 2) {
      for (int idx = t; idx < 1440; idx += 512) {
        int i = idx / 10, o = idx % 10;
        const float4* uhp = (const float4*)&uh[i * 160 + o * 16];
        const float4* vp = (const float4*)&vv[o * 16];
        float dot = 0.f;
#pragma unroll
        for (int q = 0; q < 4; ++q) {
          float4 a = uhp[q], v2 = vp[q];
          dot += a.x * v2.x + a.y * v2.y + a.z * v2.z + a.w * v2.w;
        }
        blog[idx] += dot;
      }
      __syncthreads();
    }
  }
  if (t < 160) out[B * 10 + b * 160 + t] = vv[t];
}

extern "C" void kernel_launch(void* const* d_in, const int* in_sizes, int n_in,
                              void* d_out, int out_size, void* d_ws, size_t ws_size,
                              hipStream_t stream) {
  const float* in = (const float*)d_in[0];
  const float* w1 = (const float*)d_in[1];
  const float* b1 = (const float*)d_in[2];
  const float* w2 = (const float*)d_in[3];
  const float* b2 = (const float*)d_in[4];
  const float* Wr = (const float*)d_in[5];
  float* out = (float*)d_out;
  float* ws = (float*)d_ws;
  int B = in_sizes[0] / 784;

  float* x1 = ws;                       // [B][16][20][20] = B*6400 floats
  float* u  = ws + (size_t)B * 6400;    // [B][144][8]     = B*1152 floats
  float* wT = ws + (size_t)B * 7552;    // [16][21][32][4] = 43008 floats

  transpose_w2<<<168, 256, 0, stream>>>(w2, wT);
  conv1_kernel<<<B, 320, 0, stream>>>(in, w1, b1, x1);
  conv2_kernel<<<B, 192, 0, stream>>>(x1, wT, b2, u);
  routing_kernel<<<B, 512, 0, stream>>>(u, Wr, out, B);
}

// Round 4
// 332.618 us; speedup vs baseline: 1.1783x; 1.1783x over previous
//
#include <hip/hip_runtime.h>

// CapsNet forward.
// conv1 (fp32 compute) -> x1h packed f16 [B][16][20][16dw-padded rows]
// packw2: w2 -> f16 kw-pairs wP[ci][kh][q][co][2dw]
// conv2: v_dot2_f32_f16 (f16 pairs, fp32 accum), thread=(b,co,oh) -> u [B,144,8] fp32
// routing: per-sample u_hat in LDS + 3 iters + squash -> pred, v

typedef _Float16 half2_t __attribute__((ext_vector_type(2)));

static __device__ __forceinline__ float fdot2f(half2_t a, half2_t b, float c) {
#if __has_builtin(__builtin_amdgcn_fdot2)
  return __builtin_amdgcn_fdot2(a, b, c, false);
#else
  return c + (float)a[0] * (float)b[0] + (float)a[1] * (float)b[1];
#endif
}

static __device__ __forceinline__ half2_t h2(unsigned int u) {
  return __builtin_bit_cast(half2_t, u);
}

__global__ __launch_bounds__(256) void packw2(
    const float* __restrict__ w2, unsigned int* __restrict__ wP) {
  int idx = blockIdx.x * 256 + threadIdx.x;   // ((ci*9+kh)*3+q)*32+co, 13824 total
  if (idx >= 13824) return;
  int co = idx & 31;
  int q = (idx >> 5) % 3;
  int ckh = idx / 96;
  int ci = ckh / 9, kh = ckh % 9;
  const float* wsrc = w2 + (co * 16 + ci) * 81 + kh * 9;
#pragma unroll
  for (int d = 0; d < 2; ++d) {
    int kw0 = q * 4 + d * 2, kw1 = kw0 + 1;
    half2_t h;
    h[0] = (_Float16)((kw0 < 9) ? wsrc[kw0] : 0.0f);
    h[1] = (_Float16)((kw1 < 9) ? wsrc[kw1] : 0.0f);
    wP[idx * 2 + d] = __builtin_bit_cast(unsigned int, h);
  }
}

__global__ __launch_bounds__(320) void conv1_kernel(
    const float* __restrict__ in, const float* __restrict__ w,
    const float* __restrict__ bias, unsigned int* __restrict__ x1h) {
  __shared__ __align__(16) float sIn[784];    // 28x28
  __shared__ float sW[1296];                  // 16x81
  int b = blockIdx.x, t = threadIdx.x;
  const float* inb = in + b * 784;
  for (int i = t; i < 784; i += 320) sIn[i] = inb[i];
  for (int i = t; i < 1296; i += 320) sW[i] = w[i];
  __syncthreads();
  int co = t / 20, oh = t % 20;   // 16*20 = 320 work items
  float bv = bias[co];
  float acc[20];
#pragma unroll
  for (int j = 0; j < 20; ++j) acc[j] = bv;
#pragma unroll
  for (int kh = 0; kh < 9; ++kh) {
    float r[28];
    const float4* row = (const float4*)&sIn[(oh + kh) * 28];
#pragma unroll
    for (int q = 0; q < 7; ++q) {
      float4 v = row[q];
      r[q * 4 + 0] = v.x; r[q * 4 + 1] = v.y; r[q * 4 + 2] = v.z; r[q * 4 + 3] = v.w;
    }
    const float* wr = &sW[co * 81 + kh * 9];
#pragma unroll
    for (int kw = 0; kw < 9; ++kw) {
      float wv = wr[kw];
#pragma unroll
      for (int j = 0; j < 20; ++j) acc[j] += wv * r[kw + j];
    }
  }
  // pack to f16 pairs: row = 10 dwords + 6 pad (64B-aligned rows)
  unsigned int dw[16];
#pragma unroll
  for (int j = 0; j < 10; ++j) {
    half2_t h;
    h[0] = (_Float16)acc[2 * j];
    h[1] = (_Float16)acc[2 * j + 1];
    dw[j] = __builtin_bit_cast(unsigned int, h);
  }
#pragma unroll
  for (int j = 10; j < 16; ++j) dw[j] = 0u;
  unsigned int* op = x1h + (((size_t)b * 16 + co) * 20 + oh) * 16;
#pragma unroll
  for (int q = 0; q < 4; ++q)
    *(uint4*)(op + q * 4) =
        make_uint4(dw[q * 4], dw[q * 4 + 1], dw[q * 4 + 2], dw[q * 4 + 3]);
}

// conv2: thread = (b, co, oh), lane map t = oh*32+co.
// Per (ci,kh): 3 row loads (10 f16-pair dwords) + 3 weight uint2 loads
// (coalesced over co), then 6 ow x 5 dot2 = 30 v_dot2_f32_f16.
__global__ __launch_bounds__(192) void conv2_kernel(
    const unsigned int* __restrict__ x1h, const unsigned int* __restrict__ wP,
    const float* __restrict__ bias, float* __restrict__ u) {
  int b = blockIdx.x, t = threadIdx.x;
  int oh = t >> 5, co = t & 31;
  const unsigned int* xb = x1h + (size_t)b * 5120;   // 16*20*16 dwords/sample
  float acc[6] = {0.f, 0.f, 0.f, 0.f, 0.f, 0.f};

  for (int ci = 0; ci < 16; ++ci) {
    const unsigned int* xc = xb + ci * 320;
#pragma unroll
    for (int kh = 0; kh < 9; ++kh) {
      int ih = oh * 2 + kh;
      const unsigned int* rowp = xc + ih * 16;
      uint4 ra = *(const uint4*)rowp;
      uint4 rb = *(const uint4*)(rowp + 4);
      uint2 rc = *(const uint2*)(rowp + 8);
      half2_t r2[10] = {h2(ra.x), h2(ra.y), h2(ra.z), h2(ra.w),
                        h2(rb.x), h2(rb.y), h2(rb.z), h2(rb.w),
                        h2(rc.x), h2(rc.y)};
      const unsigned int* wb = wP + (ci * 9 + kh) * 192 + co * 2;
      uint2 wa = *(const uint2*)wb;            // pairs kw(0,1),(2,3)
      uint2 wc = *(const uint2*)(wb + 64);     // pairs kw(4,5),(6,7)
      uint2 we = *(const uint2*)(wb + 128);    // pair  kw(8,pad)
      half2_t wp0 = h2(wa.x), wp1 = h2(wa.y), wp2 = h2(wc.x),
              wp3 = h2(wc.y), wp4 = h2(we.x);
#pragma unroll
      for (int ow = 0; ow < 6; ++ow) {
        float a = acc[ow];
        a = fdot2f(wp0, r2[ow + 0], a);
        a = fdot2f(wp1, r2[ow + 1], a);
        a = fdot2f(wp2, r2[ow + 2], a);
        a = fdot2f(wp3, r2[ow + 3], a);
        a = fdot2f(wp4, r2[ow + 4], a);
        acc[ow] = a;
      }
    }
  }
  float bv = bias[co];
  float* ub = u + (size_t)b * 1152;
  int ib = (co & 3) * 36 + oh * 6;
  int c8 = co >> 2;
#pragma unroll
  for (int ow = 0; ow < 6; ++ow) ub[(ib + ow) * 8 + c8] = acc[ow] + bv;
}

__global__ __launch_bounds__(512) void routing_kernel(
    const float* __restrict__ u, const float* __restrict__ W,
    float* __restrict__ out, int B) {
  __shared__ __align__(16) float uh[23040];   // u_hat [144][160]  (o*16+d)
  __shared__ __align__(16) float us[1152];    // u [144][8]
  __shared__ float blog[1440];                // b [144][10]
  __shared__ float cc[1440];                  // c [144][10]
  __shared__ __align__(16) float vv[160];     // v [10][16]
  __shared__ float ss[160];                   // s [10][16]
  int b = blockIdx.x, t = threadIdx.x;
  for (int i = t; i < 1152; i += 512) us[i] = u[b * 1152 + i];
  for (int i = t; i < 1440; i += 512) blog[i] = 0.0f;
  __syncthreads();
  const float4* W4 = (const float4*)W;
  for (int idx = t; idx < 23040; idx += 512) {
    int i = idx / 160;
    float4 wa = W4[idx * 2], wb = W4[idx * 2 + 1];
    const float4* up = (const float4*)&us[i * 8];
    float4 ua = up[0], ub2 = up[1];
    uh[idx] = wa.x * ua.x + wa.y * ua.y + wa.z * ua.z + wa.w * ua.w +
              wb.x * ub2.x + wb.y * ub2.y + wb.z * ub2.z + wb.w * ub2.w;
  }
  __syncthreads();

  for (int it = 0; it < 3; ++it) {
    if (it > 0) {
      if (t < 144) {
        const float* br = &blog[t * 10];
        float mx = br[0];
#pragma unroll
        for (int o = 1; o < 10; ++o) mx = fmaxf(mx, br[o]);
        float e[10];
        float sum = 0.f;
#pragma unroll
        for (int o = 0; o < 10; ++o) { e[o] = __expf(br[o] - mx); sum += e[o]; }
        float inv = 1.0f / sum;
#pragma unroll
        for (int o = 0; o < 10; ++o) cc[t * 10 + o] = e[o] * inv;
      }
      __syncthreads();
    }
    if (t < 160) {
      int o = t >> 4;
      float acc = 0.f;
      if (it == 0) {
        for (int i = 0; i < 144; ++i) acc += uh[i * 160 + t];
        acc *= 0.1f;
      } else {
        for (int i = 0; i < 144; ++i) acc += cc[i * 10 + o] * uh[i * 160 + t];
      }
      ss[t] = acc;
    }
    __syncthreads();
    if (t < 10) {
      float sq = 0.f;
#pragma unroll
      for (int d = 0; d < 16; ++d) { float x = ss[t * 16 + d]; sq += x * x; }
      float coef = (sq / (1.0f + sq)) / sqrtf(sq + 1e-8f);
#pragma unroll
      for (int d = 0; d < 16; ++d) vv[t * 16 + d] = coef * ss[t * 16 + d];
      if (it == 2) out[b * 10 + t] = coef * sqrtf(sq);
    }
    __syncthreads();
    if (it < 2) {
      for (int idx = t; idx < 1440; idx += 512) {
        int i = idx / 10, o = idx % 10;
        const float4* uhp = (const float4*)&uh[i * 160 + o * 16];
        const float4* vp = (const float4*)&vv[o * 16];
        float dot = 0.f;
#pragma unroll
        for (int q = 0; q < 4; ++q) {
          float4 a = uhp[q], v2 = vp[q];
          dot += a.x * v2.x + a.y * v2.y + a.z * v2.z + a.w * v2.w;
        }
        blog[idx] += dot;
      }
      __syncthreads();
    }
  }
  if (t < 160) out[B * 10 + b * 160 + t] = vv[t];
}

extern "C" void kernel_launch(void* const* d_in, const int* in_sizes, int n_in,
                              void* d_out, int out_size, void* d_ws, size_t ws_size,
                              hipStream_t stream) {
  const float* in = (const float*)d_in[0];
  const float* w1 = (const float*)d_in[1];
  const float* b1 = (const float*)d_in[2];
  const float* w2 = (const float*)d_in[3];
  const float* b2 = (const float*)d_in[4];
  const float* Wr = (const float*)d_in[5];
  float* out = (float*)d_out;
  int B = in_sizes[0] / 784;

  unsigned int* x1h = (unsigned int*)d_ws;                    // B*5120 dwords
  float* u = (float*)d_ws + (size_t)B * 5120;                 // B*1152 floats
  unsigned int* wP =
      (unsigned int*)((float*)d_ws + (size_t)B * 5120 + (size_t)B * 1152);  // 27648 dw

  packw2<<<54, 256, 0, stream>>>(w2, wP);
  conv1_kernel<<<B, 320, 0, stream>>>(in, w1, b1, x1h);
  conv2_kernel<<<B, 192, 0, stream>>>(x1h, wP, b2, u);
  routing_kernel<<<B, 512, 0, stream>>>(u, Wr, out, B);
}

// Round 5
// 306.490 us; speedup vs baseline: 1.2787x; 1.0852x over previous
//
#include <hip/hip_runtime.h>

// CapsNet forward.
// conv1 (fp32 compute) -> x1h packed f16 [B][16][20][16dw-padded rows]
// packw2: w2 -> f16 kw-pairs wP[ci][kh][q][co][2dw]
// packWr: W_route -> f16 c-pairs wPr[i][o][d][4dw]
// conv2: v_dot2_f32_f16, thread=(b,half,co,oh), split-K over ci -> u [B,144,8] fp32
// routing: f16 u_hat in LDS (46KB, 2 blocks/CU) + 3 iters fp32 -> pred, v

typedef _Float16 half2_t __attribute__((ext_vector_type(2)));

static __device__ __forceinline__ float fdot2f(half2_t a, half2_t b, float c) {
#if __has_builtin(__builtin_amdgcn_fdot2)
  return __builtin_amdgcn_fdot2(a, b, c, false);
#else
  return c + (float)a[0] * (float)b[0] + (float)a[1] * (float)b[1];
#endif
}

static __device__ __forceinline__ half2_t h2(unsigned int u) {
  return __builtin_bit_cast(half2_t, u);
}

static __device__ __forceinline__ unsigned int pkh2(float a, float b) {
  half2_t h;
  h[0] = (_Float16)a;
  h[1] = (_Float16)b;
  return __builtin_bit_cast(unsigned int, h);
}

__global__ __launch_bounds__(256) void packw2(
    const float* __restrict__ w2, unsigned int* __restrict__ wP) {
  int idx = blockIdx.x * 256 + threadIdx.x;   // ((ci*9+kh)*3+q)*32+co, 13824 total
  if (idx >= 13824) return;
  int co = idx & 31;
  int q = (idx >> 5) % 3;
  int ckh = idx / 96;
  int ci = ckh / 9, kh = ckh % 9;
  const float* wsrc = w2 + (co * 16 + ci) * 81 + kh * 9;
#pragma unroll
  for (int d = 0; d < 2; ++d) {
    int kw0 = q * 4 + d * 2, kw1 = kw0 + 1;
    float a = (kw0 < 9) ? wsrc[kw0] : 0.0f;
    float b = (kw1 < 9) ? wsrc[kw1] : 0.0f;
    wP[idx * 2 + d] = pkh2(a, b);
  }
}

// W_route [144][10][16][8] f32 -> wPr [(i*10+o)*16+d][4] f16 c-pairs
__global__ __launch_bounds__(256) void packWr(
    const float* __restrict__ W, unsigned int* __restrict__ wPr) {
  int idx = blockIdx.x * 256 + threadIdx.x;   // 92160 dwords
  if (idx >= 92160) return;
  int cp = idx & 3;
  int row = idx >> 2;
  const float* src = W + (size_t)row * 8 + cp * 2;
  wPr[idx] = pkh2(src[0], src[1]);
}

__global__ __launch_bounds__(320) void conv1_kernel(
    const float* __restrict__ in, const float* __restrict__ w,
    const float* __restrict__ bias, unsigned int* __restrict__ x1h) {
  __shared__ __align__(16) float sIn[784];    // 28x28
  __shared__ float sW[1296];                  // 16x81
  int b = blockIdx.x, t = threadIdx.x;
  const float* inb = in + b * 784;
  for (int i = t; i < 784; i += 320) sIn[i] = inb[i];
  for (int i = t; i < 1296; i += 320) sW[i] = w[i];
  __syncthreads();
  int co = t / 20, oh = t % 20;   // 16*20 = 320 work items
  float bv = bias[co];
  float acc[20];
#pragma unroll
  for (int j = 0; j < 20; ++j) acc[j] = bv;
#pragma unroll
  for (int kh = 0; kh < 9; ++kh) {
    float r[28];
    const float4* row = (const float4*)&sIn[(oh + kh) * 28];
#pragma unroll
    for (int q = 0; q < 7; ++q) {
      float4 v = row[q];
      r[q * 4 + 0] = v.x; r[q * 4 + 1] = v.y; r[q * 4 + 2] = v.z; r[q * 4 + 3] = v.w;
    }
    const float* wr = &sW[co * 81 + kh * 9];
#pragma unroll
    for (int kw = 0; kw < 9; ++kw) {
      float wv = wr[kw];
#pragma unroll
      for (int j = 0; j < 20; ++j) acc[j] += wv * r[kw + j];
    }
  }
  unsigned int dw[16];
#pragma unroll
  for (int j = 0; j < 10; ++j) dw[j] = pkh2(acc[2 * j], acc[2 * j + 1]);
#pragma unroll
  for (int j = 10; j < 16; ++j) dw[j] = 0u;
  unsigned int* op = x1h + (((size_t)b * 16 + co) * 20 + oh) * 16;
#pragma unroll
  for (int q = 0; q < 4; ++q)
    *(uint4*)(op + q * 4) =
        make_uint4(dw[q * 4], dw[q * 4 + 1], dw[q * 4 + 2], dw[q * 4 + 3]);
}

// conv2 split-K: 384 threads = 2 ci-halves x (oh*32+co). Each half does 8 ci
// with the round-4 inner loop (f16 dot2); partials merged via LDS.
__global__ __launch_bounds__(384) void conv2_kernel(
    const unsigned int* __restrict__ x1h, const unsigned int* __restrict__ wP,
    const float* __restrict__ bias, float* __restrict__ u) {
  __shared__ float part[1152];
  int b = blockIdx.x, t = threadIdx.x;
  int half = (t >= 192) ? 1 : 0;
  int tt = t - half * 192;
  int oh = tt >> 5, co = tt & 31;
  const unsigned int* xb = x1h + (size_t)b * 5120 + half * 2560;
  const unsigned int* wH = wP + half * 13824;
  float acc[6] = {0.f, 0.f, 0.f, 0.f, 0.f, 0.f};

  for (int ci = 0; ci < 8; ++ci) {
    const unsigned int* xc = xb + ci * 320;
#pragma unroll
    for (int kh = 0; kh < 9; ++kh) {
      int ih = oh * 2 + kh;
      const unsigned int* rowp = xc + ih * 16;
      uint4 ra = *(const uint4*)rowp;
      uint4 rb = *(const uint4*)(rowp + 4);
      uint2 rc = *(const uint2*)(rowp + 8);
      half2_t r2[10] = {h2(ra.x), h2(ra.y), h2(ra.z), h2(ra.w),
                        h2(rb.x), h2(rb.y), h2(rb.z), h2(rb.w),
                        h2(rc.x), h2(rc.y)};
      const unsigned int* wb = wH + (ci * 9 + kh) * 192 + co * 2;
      uint2 wa = *(const uint2*)wb;            // pairs kw(0,1),(2,3)
      uint2 wc = *(const uint2*)(wb + 64);     // pairs kw(4,5),(6,7)
      uint2 we = *(const uint2*)(wb + 128);    // pair  kw(8,pad)
      half2_t wp0 = h2(wa.x), wp1 = h2(wa.y), wp2 = h2(wc.x),
              wp3 = h2(wc.y), wp4 = h2(we.x);
#pragma unroll
      for (int ow = 0; ow < 6; ++ow) {
        float a = acc[ow];
        a = fdot2f(wp0, r2[ow + 0], a);
        a = fdot2f(wp1, r2[ow + 1], a);
        a = fdot2f(wp2, r2[ow + 2], a);
        a = fdot2f(wp3, r2[ow + 3], a);
        a = fdot2f(wp4, r2[ow + 4], a);
        acc[ow] = a;
      }
    }
  }
  int ib = (co & 3) * 36 + oh * 6;
  int c8 = co >> 2;
  if (half) {
#pragma unroll
    for (int ow = 0; ow < 6; ++ow) part[(ib + ow) * 8 + c8] = acc[ow];
  }
  __syncthreads();
  if (!half) {
    float bv = bias[co];
    float* ub = u + (size_t)b * 1152;
#pragma unroll
    for (int ow = 0; ow < 6; ++ow)
      ub[(ib + ow) * 8 + c8] = acc[ow] + part[(ib + ow) * 8 + c8] + bv;
  }
}

// routing: 256 threads/sample. u_hat f16 in LDS (d-pairs), W f16 from global,
// all accumulation fp32. ~62 KB LDS -> 2 blocks/CU.
__global__ __launch_bounds__(256) void routing_kernel(
    const float* __restrict__ u, const unsigned int* __restrict__ wPr,
    float* __restrict__ out, int B) {
  __shared__ unsigned int uhh[11520];   // uh [144][o*8+dp] f16 d-pairs
  __shared__ unsigned int ush[576];     // u  [144][4] f16 c-pairs
  __shared__ float blog[1440];          // b [144][10]
  __shared__ float cc[1440];            // c [144][10]
  __shared__ float ss[160];             // s [10][16]
  __shared__ float vv[160];             // v [10][16]
  __shared__ unsigned int vvh[80];      // v f16 d-pairs
  int b = blockIdx.x, t = threadIdx.x;
  const float* ub = u + (size_t)b * 1152;
  for (int i = t; i < 576; i += 256) {
    float2 p = *(const float2*)(ub + i * 2);
    ush[i] = pkh2(p.x, p.y);
  }
  for (int i = t; i < 1440; i += 256) blog[i] = 0.f;
  __syncthreads();
  const uint4* W4 = (const uint4*)wPr;
  for (int idx = t; idx < 11520; idx += 256) {
    int i = idx / 80, rem = idx - i * 80;   // rem = o*8+dp
    int o = rem >> 3, dp = rem & 7;
    int wrow = (i * 10 + o) * 16 + dp * 2;
    uint4 w0 = W4[wrow];         // W row d=2dp   (8 f16)
    uint4 w1 = W4[wrow + 1];     // W row d=2dp+1
    const uint2* up = (const uint2*)&ush[i * 4];
    uint2 ua = up[0], ubp = up[1];
    half2_t u0 = h2(ua.x), u1 = h2(ua.y), u2 = h2(ubp.x), u3 = h2(ubp.y);
    float a0 = fdot2f(h2(w0.x), u0,
               fdot2f(h2(w0.y), u1,
               fdot2f(h2(w0.z), u2, fdot2f(h2(w0.w), u3, 0.f))));
    float a1 = fdot2f(h2(w1.x), u0,
               fdot2f(h2(w1.y), u1,
               fdot2f(h2(w1.z), u2, fdot2f(h2(w1.w), u3, 0.f))));
    uhh[idx] = pkh2(a0, a1);
  }
  __syncthreads();

  for (int it = 0; it < 3; ++it) {
    if (it > 0) {
      if (t < 144) {
        const float* br = &blog[t * 10];
        float mx = br[0];
#pragma unroll
        for (int o = 1; o < 10; ++o) mx = fmaxf(mx, br[o]);
        float e[10];
        float sum = 0.f;
#pragma unroll
        for (int o = 0; o < 10; ++o) { e[o] = __expf(br[o] - mx); sum += e[o]; }
        float inv = 1.0f / sum;
#pragma unroll
        for (int o = 0; o < 10; ++o) cc[t * 10 + o] = e[o] * inv;
      }
      __syncthreads();
    }
    // s[o][d-pair]: 80 threads
    if (t < 80) {
      int o = t >> 3;
      float a0 = 0.f, a1 = 0.f;
      if (it == 0) {
        for (int i = 0; i < 144; ++i) {
          half2_t h = h2(uhh[i * 80 + t]);
          a0 += (float)h[0]; a1 += (float)h[1];
        }
        a0 *= 0.1f; a1 *= 0.1f;
      } else {
        for (int i = 0; i < 144; ++i) {
          float c = cc[i * 10 + o];
          half2_t h = h2(uhh[i * 80 + t]);
          a0 += c * (float)h[0]; a1 += c * (float)h[1];
        }
      }
      ss[t * 2] = a0; ss[t * 2 + 1] = a1;
    }
    __syncthreads();
    if (t < 10) {
      float sq = 0.f;
#pragma unroll
      for (int d = 0; d < 16; ++d) { float x = ss[t * 16 + d]; sq += x * x; }
      float coef = (sq / (1.0f + sq)) / sqrtf(sq + 1e-8f);
#pragma unroll
      for (int q = 0; q < 8; ++q) {
        float v0 = coef * ss[t * 16 + 2 * q];
        float v1 = coef * ss[t * 16 + 2 * q + 1];
        vv[t * 16 + 2 * q] = v0;
        vv[t * 16 + 2 * q + 1] = v1;
        vvh[t * 8 + q] = pkh2(v0, v1);
      }
      if (it == 2) out[b * 10 + t] = coef * sqrtf(sq);   // pred = ||v||
    }
    __syncthreads();
    if (it < 2) {
      for (int idx = t; idx < 1440; idx += 256) {
        int i = idx / 10, o = idx - i * 10;
        const uint2* uhp = (const uint2*)&uhh[i * 80 + o * 8];
        const uint2* vp = (const uint2*)&vvh[o * 8];
        float dot = 0.f;
#pragma unroll
        for (int q = 0; q < 4; ++q) {
          uint2 A = uhp[q], V = vp[q];
          dot = fdot2f(h2(A.x), h2(V.x), fdot2f(h2(A.y), h2(V.y), dot));
        }
        blog[idx] += dot;
      }
      __syncthreads();
    }
  }
  if (t < 160) out[B * 10 + b * 160 + t] = vv[t];
}

extern "C" void kernel_launch(void* const* d_in, const int* in_sizes, int n_in,
                              void* d_out, int out_size, void* d_ws, size_t ws_size,
                              hipStream_t stream) {
  const float* in = (const float*)d_in[0];
  const float* w1 = (const float*)d_in[1];
  const float* b1 = (const float*)d_in[2];
  const float* w2 = (const float*)d_in[3];
  const float* b2 = (const float*)d_in[4];
  const float* Wr = (const float*)d_in[5];
  float* out = (float*)d_out;
  int B = in_sizes[0] / 784;

  unsigned int* x1h = (unsigned int*)d_ws;                      // B*5120 dw
  float* u = (float*)d_ws + (size_t)B * 5120;                   // B*1152 f32
  unsigned int* wP = (unsigned int*)d_ws + (size_t)B * 6272;    // 27648 dw
  unsigned int* wPr = wP + 27648;                               // 92160 dw

  packw2<<<54, 256, 0, stream>>>(w2, wP);
  packWr<<<360, 256, 0, stream>>>(Wr, wPr);
  conv1_kernel<<<B, 320, 0, stream>>>(in, w1, b1, x1h);
  conv2_kernel<<<B, 384, 0, stream>>>(x1h, wP, b2, u);
  routing_kernel<<<B, 256, 0, stream>>>(u, wPr, out, B);
}

// Round 6
// 163.992 us; speedup vs baseline: 2.3898x; 1.8689x over previous
//
#include <hip/hip_runtime.h>

// CapsNet forward.
// conv1 (fp32 compute) -> x1t f16 [B][ih=20][iw=20][ci=16]  (ci innermost)
// packWB: w2 -> MFMA B-fragments wBg[kh][kw][lane][8] f16
// conv2: v_mfma_f32_32x32x16_f16 GEMM (M=n=(b,oh,ow), N=co, K=ci per (kh,kw))
// packWr: W_route -> f16 c-pairs; routing: f16 u_hat in LDS + 3 iters fp32

typedef _Float16 half2_t __attribute__((ext_vector_type(2)));
typedef _Float16 f16x8 __attribute__((ext_vector_type(8)));
typedef float f32x16 __attribute__((ext_vector_type(16)));

static __device__ __forceinline__ float fdot2f(half2_t a, half2_t b, float c) {
#if __has_builtin(__builtin_amdgcn_fdot2)
  return __builtin_amdgcn_fdot2(a, b, c, false);
#else
  return c + (float)a[0] * (float)b[0] + (float)a[1] * (float)b[1];
#endif
}

static __device__ __forceinline__ half2_t h2(unsigned int u) {
  return __builtin_bit_cast(half2_t, u);
}

static __device__ __forceinline__ unsigned int pkh2(float a, float b) {
  half2_t h;
  h[0] = (_Float16)a;
  h[1] = (_Float16)b;
  return __builtin_bit_cast(unsigned int, h);
}

static __device__ __forceinline__ f32x16 zero16() {
  f32x16 z = {0.f, 0.f, 0.f, 0.f, 0.f, 0.f, 0.f, 0.f,
              0.f, 0.f, 0.f, 0.f, 0.f, 0.f, 0.f, 0.f};
  return z;
}

// w2[co][ci][kh][kw] f32 -> wBg[((kh*9+kw)*64 + lane)*8 + j] f16
// where co = lane&31, ci = (lane>>5)*8 + j   (exact B-fragment order)
__global__ __launch_bounds__(256) void packWB(
    const float* __restrict__ w2, _Float16* __restrict__ wBg) {
  int idx = blockIdx.x * 256 + threadIdx.x;
  if (idx >= 41472) return;
  int j = idx & 7;
  int lane = (idx >> 3) & 63;
  int step = idx >> 9;
  int kh = step / 9, kw = step - kh * 9;
  int co = lane & 31, ci = (lane >> 5) * 8 + j;
  wBg[idx] = (_Float16)w2[(co * 16 + ci) * 81 + kh * 9 + kw];
}

// W_route [144][10][16][8] f32 -> wPr [(i*10+o)*16+d][4] f16 c-pairs
__global__ __launch_bounds__(256) void packWr(
    const float* __restrict__ W, unsigned int* __restrict__ wPr) {
  int idx = blockIdx.x * 256 + threadIdx.x;   // 92160 dwords
  if (idx >= 92160) return;
  int cp = idx & 3;
  int row = idx >> 2;
  const float* src = W + (size_t)row * 8 + cp * 2;
  wPr[idx] = pkh2(src[0], src[1]);
}

__global__ __launch_bounds__(320) void conv1_kernel(
    const float* __restrict__ in, const float* __restrict__ w,
    const float* __restrict__ bias, _Float16* __restrict__ x1t) {
  __shared__ __align__(16) float sIn[784];      // 28x28
  __shared__ float sW[1296];                    // 16x81
  __shared__ __align__(16) _Float16 sOut[6400]; // [ih][iw][ci]
  int b = blockIdx.x, t = threadIdx.x;
  const float* inb = in + b * 784;
  for (int i = t; i < 784; i += 320) sIn[i] = inb[i];
  for (int i = t; i < 1296; i += 320) sW[i] = w[i];
  __syncthreads();
  int co = t / 20, oh = t % 20;   // 16*20 = 320 work items
  float bv = bias[co];
  float acc[20];
#pragma unroll
  for (int j = 0; j < 20; ++j) acc[j] = bv;
#pragma unroll
  for (int kh = 0; kh < 9; ++kh) {
    float r[28];
    const float4* row = (const float4*)&sIn[(oh + kh) * 28];
#pragma unroll
    for (int q = 0; q < 7; ++q) {
      float4 v = row[q];
      r[q * 4 + 0] = v.x; r[q * 4 + 1] = v.y; r[q * 4 + 2] = v.z; r[q * 4 + 3] = v.w;
    }
    const float* wr = &sW[co * 81 + kh * 9];
#pragma unroll
    for (int kw = 0; kw < 9; ++kw) {
      float wv = wr[kw];
#pragma unroll
      for (int j = 0; j < 20; ++j) acc[j] += wv * r[kw + j];
    }
  }
  // transpose to [ih][iw][ci] via LDS
#pragma unroll
  for (int j = 0; j < 20; ++j) sOut[(oh * 20 + j) * 16 + co] = (_Float16)acc[j];
  __syncthreads();
  const unsigned int* s4 = (const unsigned int*)sOut;
  unsigned int* g4 = (unsigned int*)(x1t + (size_t)b * 6400);
  for (int i = t; i < 3200; i += 320) g4[i] = s4[i];
}

// conv2 MFMA: block = 8 samples (288 rows = 9 M-tiles of 32), 4 waves.
// A[row=n][k=ci] from LDS x1 tile (ds_read_b128, ci innermost);
// B[k=ci][col=co] fragments staged per-kh from wBg.
__global__ __launch_bounds__(256) void conv2_kernel(
    const _Float16* __restrict__ x1t, const _Float16* __restrict__ wBg,
    const float* __restrict__ bias, float* __restrict__ u) {
  __shared__ __align__(16) _Float16 sX[51200];  // 8 x [400][16]
  __shared__ __align__(16) _Float16 sB[4608];   // [kw 9][lane 64][8]
  int t = threadIdx.x;
  int bbase = blockIdx.x * 8;
  {
    const uint4* g = (const uint4*)(x1t + (size_t)bbase * 6400);
    uint4* s = (uint4*)sX;
#pragma unroll
    for (int i = 0; i < 25; ++i) s[t + i * 256] = g[t + i * 256];
  }
  int wv = t >> 6, lane = t & 63;
  int l31 = lane & 31, half = lane >> 5;
  // per-tile per-lane A base (f16 units): s*6400 + (2oh*20 + 2ow)*16 + half*8
  int tbase0 = 0, tbase1 = 0, tbase2 = 0;
  {
    int r = wv * 32 + l31;
    int s = r / 36, pos = r - s * 36, oh = pos / 6, ow = pos - oh * 6;
    tbase0 = s * 6400 + (oh * 40 + ow * 2) * 16 + half * 8;
    r += 128;
    s = r / 36; pos = r - s * 36; oh = pos / 6; ow = pos - oh * 6;
    tbase1 = s * 6400 + (oh * 40 + ow * 2) * 16 + half * 8;
    if (wv == 0) {
      r = 256 + l31;
      s = r / 36; pos = r - s * 36; oh = pos / 6; ow = pos - oh * 6;
      tbase2 = s * 6400 + (oh * 40 + ow * 2) * 16 + half * 8;
    }
  }
  f32x16 acc0 = zero16(), acc1 = zero16(), acc2 = zero16();

  for (int kh = 0; kh < 9; ++kh) {
    __syncthreads();   // prior compute done reading sB (and, first iter, sX staged)
    {
      const unsigned int* g = (const unsigned int*)(wBg + kh * 4608);
      unsigned int* s = (unsigned int*)sB;
#pragma unroll
      for (int i = 0; i < 9; ++i) s[t + i * 256] = g[t + i * 256];
    }
    __syncthreads();
    int abase = kh * 320;
#pragma unroll
    for (int kw = 0; kw < 9; ++kw) {
      f16x8 bf = *(const f16x8*)(sB + kw * 512 + lane * 8);
      f16x8 a0 = *(const f16x8*)(sX + tbase0 + abase + kw * 16);
      acc0 = __builtin_amdgcn_mfma_f32_32x32x16_f16(a0, bf, acc0, 0, 0, 0);
      f16x8 a1 = *(const f16x8*)(sX + tbase1 + abase + kw * 16);
      acc1 = __builtin_amdgcn_mfma_f32_32x32x16_f16(a1, bf, acc1, 0, 0, 0);
      if (wv == 0) {
        f16x8 a2 = *(const f16x8*)(sX + tbase2 + abase + kw * 16);
        acc2 = __builtin_amdgcn_mfma_f32_32x32x16_f16(a2, bf, acc2, 0, 0, 0);
      }
    }
  }
  // store: C col = l31 = co; row-in-tile = (reg&3) + 8*(reg>>2) + 4*half
  float bv = bias[l31];
  int c8 = l31 >> 2;
  int ibco = (l31 & 3) * 36;
#pragma unroll
  for (int reg = 0; reg < 16; ++reg) {
    int rbase = (reg & 3) + 8 * (reg >> 2) + 4 * half;
    {
      int r = wv * 32 + rbase;
      int s = r / 36, pos = r - s * 36;
      u[(size_t)(bbase + s) * 1152 + (ibco + pos) * 8 + c8] = acc0[reg] + bv;
    }
    {
      int r = wv * 32 + 128 + rbase;
      int s = r / 36, pos = r - s * 36;
      u[(size_t)(bbase + s) * 1152 + (ibco + pos) * 8 + c8] = acc1[reg] + bv;
    }
    if (wv == 0) {
      int r = 256 + rbase;
      int s = r / 36, pos = r - s * 36;
      u[(size_t)(bbase + s) * 1152 + (ibco + pos) * 8 + c8] = acc2[reg] + bv;
    }
  }
}

// routing: 256 threads/sample. u_hat f16 in LDS (d-pairs), W f16 from global,
// all accumulation fp32. ~62 KB LDS -> 2 blocks/CU.
__global__ __launch_bounds__(256) void routing_kernel(
    const float* __restrict__ u, const unsigned int* __restrict__ wPr,
    float* __restrict__ out, int B) {
  __shared__ unsigned int uhh[11520];   // uh [144][o*8+dp] f16 d-pairs
  __shared__ unsigned int ush[576];     // u  [144][4] f16 c-pairs
  __shared__ float blog[1440];          // b [144][10]
  __shared__ float cc[1440];            // c [144][10]
  __shared__ float ss[160];             // s [10][16]
  __shared__ float vv[160];             // v [10][16]
  __shared__ unsigned int vvh[80];      // v f16 d-pairs
  int b = blockIdx.x, t = threadIdx.x;
  const float* ub = u + (size_t)b * 1152;
  for (int i = t; i < 576; i += 256) {
    float2 p = *(const float2*)(ub + i * 2);
    ush[i] = pkh2(p.x, p.y);
  }
  for (int i = t; i < 1440; i += 256) blog[i] = 0.f;
  __syncthreads();
  const uint4* W4 = (const uint4*)wPr;
  for (int idx = t; idx < 11520; idx += 256) {
    int i = idx / 80, rem = idx - i * 80;   // rem = o*8+dp
    int o = rem >> 3, dp = rem & 7;
    int wrow = (i * 10 + o) * 16 + dp * 2;
    uint4 w0 = W4[wrow];         // W row d=2dp   (8 f16)
    uint4 w1 = W4[wrow + 1];     // W row d=2dp+1
    const uint2* up = (const uint2*)&ush[i * 4];
    uint2 ua = up[0], ubp = up[1];
    half2_t u0 = h2(ua.x), u1 = h2(ua.y), u2 = h2(ubp.x), u3 = h2(ubp.y);
    float a0 = fdot2f(h2(w0.x), u0,
               fdot2f(h2(w0.y), u1,
               fdot2f(h2(w0.z), u2, fdot2f(h2(w0.w), u3, 0.f))));
    float a1 = fdot2f(h2(w1.x), u0,
               fdot2f(h2(w1.y), u1,
               fdot2f(h2(w1.z), u2, fdot2f(h2(w1.w), u3, 0.f))));
    uhh[idx] = pkh2(a0, a1);
  }
  __syncthreads();

  for (int it = 0; it < 3; ++it) {
    if (it > 0) {
      if (t < 144) {
        const float* br = &blog[t * 10];
        float mx = br[0];
#pragma unroll
        for (int o = 1; o < 10; ++o) mx = fmaxf(mx, br[o]);
        float e[10];
        float sum = 0.f;
#pragma unroll
        for (int o = 0; o < 10; ++o) { e[o] = __expf(br[o] - mx); sum += e[o]; }
        float inv = 1.0f / sum;
#pragma unroll
        for (int o = 0; o < 10; ++o) cc[t * 10 + o] = e[o] * inv;
      }
      __syncthreads();
    }
    // s[o][d-pair]: 80 threads
    if (t < 80) {
      int o = t >> 3;
      float a0 = 0.f, a1 = 0.f;
      if (it == 0) {
        for (int i = 0; i < 144; ++i) {
          half2_t h = h2(uhh[i * 80 + t]);
          a0 += (float)h[0]; a1 += (float)h[1];
        }
        a0 *= 0.1f; a1 *= 0.1f;
      } else {
        for (int i = 0; i < 144; ++i) {
          float c = cc[i * 10 + o];
          half2_t h = h2(uhh[i * 80 + t]);
          a0 += c * (float)h[0]; a1 += c * (float)h[1];
        }
      }
      ss[t * 2] = a0; ss[t * 2 + 1] = a1;
    }
    __syncthreads();
    if (t < 10) {
      float sq = 0.f;
#pragma unroll
      for (int d = 0; d < 16; ++d) { float x = ss[t * 16 + d]; sq += x * x; }
      float coef = (sq / (1.0f + sq)) / sqrtf(sq + 1e-8f);
#pragma unroll
      for (int q = 0; q < 8; ++q) {
        float v0 = coef * ss[t * 16 + 2 * q];
        float v1 = coef * ss[t * 16 + 2 * q + 1];
        vv[t * 16 + 2 * q] = v0;
        vv[t * 16 + 2 * q + 1] = v1;
        vvh[t * 8 + q] = pkh2(v0, v1);
      }
      if (it == 2) out[b * 10 + t] = coef * sqrtf(sq);   // pred = ||v||
    }
    __syncthreads();
    if (it < 2) {
      for (int idx = t; idx < 1440; idx += 256) {
        int i = idx / 10, o = idx - i * 10;
        const uint2* uhp = (const uint2*)&uhh[i * 80 + o * 8];
        const uint2* vp = (const uint2*)&vvh[o * 8];
        float dot = 0.f;
#pragma unroll
        for (int q = 0; q < 4; ++q) {
          uint2 A = uhp[q], V = vp[q];
          dot = fdot2f(h2(A.x), h2(V.x), fdot2f(h2(A.y), h2(V.y), dot));
        }
        blog[idx] += dot;
      }
      __syncthreads();
    }
  }
  if (t < 160) out[B * 10 + b * 160 + t] = vv[t];
}

extern "C" void kernel_launch(void* const* d_in, const int* in_sizes, int n_in,
                              void* d_out, int out_size, void* d_ws, size_t ws_size,
                              hipStream_t stream) {
  const float* in = (const float*)d_in[0];
  const float* w1 = (const float*)d_in[1];
  const float* b1 = (const float*)d_in[2];
  const float* w2 = (const float*)d_in[3];
  const float* b2 = (const float*)d_in[4];
  const float* Wr = (const float*)d_in[5];
  float* out = (float*)d_out;
  int B = in_sizes[0] / 784;
  float* wsf = (float*)d_ws;

  _Float16* x1t = (_Float16*)wsf;                         // B*6400 f16 = B*3200 f
  float* u = wsf + (size_t)B * 3200;                      // B*1152 f32
  _Float16* wBg = (_Float16*)(wsf + (size_t)B * 4352);    // 41472 f16 = 20736 f
  unsigned int* wPr = (unsigned int*)(wsf + (size_t)B * 4352 + 20736);  // 92160 dw

  packWB<<<162, 256, 0, stream>>>(w2, wBg);
  packWr<<<360, 256, 0, stream>>>(Wr, wPr);
  conv1_kernel<<<B, 320, 0, stream>>>(in, w1, b1, x1t);
  conv2_kernel<<<B / 8, 256, 0, stream>>>(x1t, wBg, b2, u);
  routing_kernel<<<B, 256, 0, stream>>>(u, wPr, out, B);
}